// Round 13
// baseline (124.266 us; speedup 1.0000x reference)
//
#include <hip/hip_runtime.h>

// Problem constants (reference: N=32768, M=8192, D=64, fp32)
#define N_ROWS 32768
#define M_COLS 8192
#define D_DIM  64
#define JC     8                      // j-chunks (grid.y)
#define PBLOCK 256                    // prep/reduce block size
#define GBLOCK 128                    // partial_min: 2 waves/block
#define GROUPS 4                      // 16-row groups per wave -> 64 rows/wave
#define ROWS_PER_BLOCK 128            // 2 waves x 64 rows; grid.x=256 -> 8 blocks/CU
#define CHUNK  (M_COLS / JC)          // 1024 j per chunk
#define TJ     64                     // j per LDS tile (64 rows x 128 B = 8 KB)
#define NTILE  (CHUNK / TJ)           // 16 tiles per chunk

typedef _Float16 v8h __attribute__((ext_vector_type(8)));
typedef _Float16 v4h __attribute__((ext_vector_type(4)));
typedef float    v4f __attribute__((ext_vector_type(4)));

// ---------- kernel 1: yh = (half)y, th4[j] = splat4((psi[j]-||y_j||^2)/2); zero out ----------
__global__ __launch_bounds__(PBLOCK) void prep_kernel(
    const float* __restrict__ y, const float* __restrict__ psi,
    _Float16* __restrict__ yh, float* __restrict__ th4, float* __restrict__ out) {
    const int tid = threadIdx.x;
    if (blockIdx.x == 0 && tid == 0) out[0] = 0.f;   // atomic accumulator init
    const int j = blockIdx.x * 16 + (tid >> 4);  // y row
    const int n = tid & 15;                      // 4-elem segment
    const float4 v = *(const float4*)(y + (size_t)j * D_DIM + n * 4);
    float s = v.x * v.x + v.y * v.y + v.z * v.z + v.w * v.w;
    v4h hv = { (_Float16)v.x, (_Float16)v.y, (_Float16)v.z, (_Float16)v.w };
    *(v4h*)(yh + (size_t)j * D_DIM + n * 4) = hv;
#pragma unroll
    for (int m = 1; m < 16; m <<= 1) s += __shfl_xor(s, m, 64);
    if (n == 0) {
        const float t = 0.5f * (psi[j] - s);
        float4 t4 = { t, t, t, t };              // pre-splatted MFMA C-quad
        *(float4*)(th4 + (size_t)j * 4) = t4;
    }
}

// ---------- kernel 2: MFMA partial min over a j-chunk ----------
// part[jc*N + i] = min_{j in chunk} (t[j] - 2<x_i,y_j>) = -2 max_j(<x_i,y_j>+th[j])
// 2-wave blocks, GROUPS=4, TJ=64: 8 blocks/CU = 8 independent barrier groups
// at 16 waves/CU (4/SIMD). Same total MFMA / ds_read / A-prologue as R10;
// only the staging fetch doubles (absorbed by L2 BW).
__global__ __launch_bounds__(GBLOCK) void partial_min_kernel(
    const float* __restrict__ x, const _Float16* __restrict__ yh,
    const float* __restrict__ th4, float* __restrict__ part) {
    __shared__ __align__(16) _Float16 sY[2][TJ * D_DIM];  // 2 x 8 KB
    __shared__ __align__(16) float    sTh4[2][TJ * 4];    // 2 x 1 KB

    const int tid  = threadIdx.x;
    const int lane = tid & 63, wave = tid >> 6;           // wave in {0,1}
    const int q = lane >> 4, n = lane & 15;
    const int jc    = blockIdx.y;
    const int jbase = jc * CHUNK;
    const int i_wave = blockIdx.x * ROWS_PER_BLOCK + wave * (GROUPS * 16);

    // A-frags: 4 row-groups x 2 k-chunks, loaded once from fp32 x, cvt to f16.
    v8h a[GROUPS][2];
#pragma unroll
    for (int g = 0; g < GROUPS; ++g) {
        const float* px = x + (size_t)(i_wave + g * 16 + n) * D_DIM + q * 8;
#pragma unroll
        for (int c = 0; c < 2; ++c) {
            float4 f0 = *(const float4*)(px + c * 32);
            float4 f1 = *(const float4*)(px + c * 32 + 4);
            v8h av = { (_Float16)f0.x, (_Float16)f0.y, (_Float16)f0.z, (_Float16)f0.w,
                       (_Float16)f1.x, (_Float16)f1.y, (_Float16)f1.z, (_Float16)f1.w };
            a[g][c] = av;
        }
    }

    float maxs[GROUPS][4];
#pragma unroll
    for (int g = 0; g < GROUPS; ++g)
#pragma unroll
        for (int r = 0; r < 4; ++r) maxs[g][r] = -INFINITY;

    // ---- async stage of tile t into buffer b (XOR-swizzled on the GLOBAL side) ----
    // LDS 16B-slot sIdx holds (row = sIdx/8, chunk = (sIdx%8) ^ (row&7)).
    // y-tile: 512 slots, 128 lanes -> 4 rounds. th4-tile: 64 slots via wave 0.
    auto stage = [&](int t, int b) {
#pragma unroll
        for (int k = 0; k < 4; ++k) {
            const int sIdx = (k * 2 + wave) * 64 + lane;     // [0,512)
            const int row  = sIdx >> 3;
            const int c    = (sIdx & 7) ^ (row & 7);
            const _Float16* g = yh + (size_t)(jbase + t * TJ + row) * D_DIM + c * 8;
            __builtin_amdgcn_global_load_lds(
                (const __attribute__((address_space(1))) void*)g,
                (__attribute__((address_space(3))) void*)(&sY[b][(size_t)(k * 2 + wave) * 512]),
                16, 0, 0);
        }
        if (wave == 0) {  // th4 tile: 64 quads = 1 KB (lane i -> base + i*16)
            const float* gt_ = th4 + (size_t)(jbase + t * TJ + lane) * 4;
            __builtin_amdgcn_global_load_lds(
                (const __attribute__((address_space(1))) void*)gt_,
                (__attribute__((address_space(3))) void*)(&sTh4[b][0]),
                16, 0, 0);
        }
    };

    stage(0, 0);
    __syncthreads();  // drains vmcnt(0): tile 0 resident

    const int sl0 = q ^ (n & 7);  // swizzled slot for chunk q of row (..8k+n)

    for (int t = 0; t < NTILE; ++t) {
        const int cur = t & 1;
        if (t + 1 < NTILE) stage(t + 1, cur ^ 1);  // prefetch under compute

        const _Float16* buf = &sY[cur][0];
        const float* tbuf = &sTh4[cur][0];
#pragma unroll 4
        for (int ss = 0; ss < TJ / 16; ++ss) {
            // row in tile = ss*16+n (row&7 == n&7); chunk q at slot sl0, q+4 at sl0^4
            const v8h b0 = *(const v8h*)(buf + (ss * 16 + n) * 64 + sl0 * 8);
            const v8h b1 = *(const v8h*)(buf + (ss * 16 + n) * 64 + (sl0 ^ 4) * 8);
            // C-quad (th splat) straight from LDS: 1 ds_read_b128, zero movs
            const v4f tv4 = *(const v4f*)(tbuf + (ss * 16 + n) * 4);
#pragma unroll
            for (int g = 0; g < GROUPS; ++g) {
                v4f acc = __builtin_amdgcn_mfma_f32_16x16x32_f16(a[g][0], b0, tv4, 0, 0, 0);
                acc     = __builtin_amdgcn_mfma_f32_16x16x32_f16(a[g][1], b1, acc, 0, 0, 0);
#pragma unroll
                for (int r = 0; r < 4; ++r)
                    maxs[g][r] = fmaxf(maxs[g][r], acc[r]);
            }
        }
        __syncthreads();  // all waves done reading buf `cur`; prefetch drained
    }

    // reduce max across the 16 j-phase lanes (lane bits 0..3), store -2*max
#pragma unroll
    for (int g = 0; g < GROUPS; ++g) {
#pragma unroll
        for (int r = 0; r < 4; ++r) {
            float v = maxs[g][r];
#pragma unroll
            for (int m = 1; m < 16; m <<= 1)
                v = fmaxf(v, __shfl_xor(v, m, 64));
            if (n == 0)
                part[(size_t)jc * N_ROWS + i_wave + g * 16 + q * 4 + r] = -2.f * v;
        }
    }
}

// ---------- kernel 3: fused reduce ----------
// out += [ sum_i min_c part[c][i] + sum(x^2) ] / N + sum(psi) / M
__global__ __launch_bounds__(PBLOCK) void reduce_kernel(
    const float* __restrict__ part, const float* __restrict__ x,
    const float* __restrict__ psi, float* __restrict__ out) {
    const int tid = threadIdx.x;
    const int gt  = blockIdx.x * PBLOCK + tid;    // [0, 32768)
    float m = part[gt];
#pragma unroll
    for (int c = 1; c < JC; ++c)
        m = fminf(m, part[(size_t)c * N_ROWS + gt]);
    float s = m;
    const float4* xv = (const float4*)x;          // N*D/4 = 524288 float4
    float x2 = 0.f;
#pragma unroll
    for (int k = 0; k < 16; ++k) {
        float4 v = xv[gt + k * 32768];
        x2 += v.x * v.x + v.y * v.y + v.z * v.z + v.w * v.w;
    }
    s = (s + x2) * (1.f / (float)N_ROWS);
    if (gt < M_COLS) s += psi[gt] * (1.f / (float)M_COLS);
    for (int off = 32; off > 0; off >>= 1) s += __shfl_down(s, off, 64);
    __shared__ float tmp[4];
    if ((tid & 63) == 0) tmp[tid >> 6] = s;
    __syncthreads();
    if (tid == 0) atomicAdd(out, tmp[0] + tmp[1] + tmp[2] + tmp[3]);
}

extern "C" void kernel_launch(void* const* d_in, const int* in_sizes, int n_in,
                              void* d_out, int out_size, void* d_ws, size_t ws_size,
                              hipStream_t stream) {
    const float* x   = (const float*)d_in[0];   // [N,D]
    const float* y   = (const float*)d_in[1];   // [M,D]
    const float* psi = (const float*)d_in[2];   // [M]
    float* out = (float*)d_out;

    // workspace layout
    float* part = (float*)d_ws;                       // JC*N floats = 1 MB
    float* th4  = part + (size_t)JC * N_ROWS;         // M*4 floats = 128 KB
    _Float16* yh = (_Float16*)(th4 + (size_t)M_COLS * 4);  // M*D halves = 1 MB

    prep_kernel<<<M_COLS / 16, PBLOCK, 0, stream>>>(y, psi, yh, th4, out);
    partial_min_kernel<<<dim3(N_ROWS / ROWS_PER_BLOCK, JC), GBLOCK, 0, stream>>>(x, yh, th4, part);
    reduce_kernel<<<N_ROWS / PBLOCK, PBLOCK, 0, stream>>>(part, x, psi, out);
}

// Round 14
// 101.418 us; speedup vs baseline: 1.2253x; 1.2253x over previous
//
#include <hip/hip_runtime.h>

// Problem constants (reference: N=32768, M=8192, D=64, fp32)
#define N_ROWS 32768
#define M_COLS 8192
#define D_DIM  64
#define JC     8                      // j-chunks (grid.y)
#define PBLOCK 256                    // prep/reduce block size
#define BLOCK  256                    // partial_min: 4 waves/block (R10 optimum)
#define GROUPS 4                      // 16-row groups per wave -> 64 rows/wave
#define ROWS_PER_BLOCK 256            // 4 waves x 64 rows; grid.x=128 -> 4 blocks/CU
#define CHUNK  (M_COLS / JC)          // 1024 j per chunk
#define TJ     128                    // j per LDS tile (128 rows x 128 B = 16 KB)
#define NTILE  (CHUNK / TJ)           // 8 tiles per chunk

typedef _Float16 v8h __attribute__((ext_vector_type(8)));
typedef _Float16 v4h __attribute__((ext_vector_type(4)));
typedef float    v4f __attribute__((ext_vector_type(4)));

// ---------- kernel 1: yh=(half)y, th4[j]=splat4((psi-||y||^2)/2), xh=(half)x ----------
// blocks [0, M/16): y rows (+ th4); blocks [M/16, M/16+N/16): x rows.
__global__ __launch_bounds__(PBLOCK) void prep_kernel(
    const float* __restrict__ y, const float* __restrict__ psi,
    const float* __restrict__ x, _Float16* __restrict__ yh,
    float* __restrict__ th4, _Float16* __restrict__ xh, float* __restrict__ out) {
    const int tid = threadIdx.x;
    const int bid = blockIdx.x;
    const int n = tid & 15;                      // 4-elem segment
    if (bid < M_COLS / 16) {
        if (bid == 0 && tid == 0) out[0] = 0.f;  // atomic accumulator init
        const int j = bid * 16 + (tid >> 4);     // y row
        const float4 v = *(const float4*)(y + (size_t)j * D_DIM + n * 4);
        float s = v.x * v.x + v.y * v.y + v.z * v.z + v.w * v.w;
        v4h hv = { (_Float16)v.x, (_Float16)v.y, (_Float16)v.z, (_Float16)v.w };
        *(v4h*)(yh + (size_t)j * D_DIM + n * 4) = hv;
#pragma unroll
        for (int m = 1; m < 16; m <<= 1) s += __shfl_xor(s, m, 64);
        if (n == 0) {
            const float t = 0.5f * (psi[j] - s);
            float4 t4 = { t, t, t, t };          // pre-splatted MFMA C-quad
            *(float4*)(th4 + (size_t)j * 4) = t4;
        }
    } else {
        const int i = (bid - M_COLS / 16) * 16 + (tid >> 4);  // x row
        const float4 v = *(const float4*)(x + (size_t)i * D_DIM + n * 4);
        v4h hv = { (_Float16)v.x, (_Float16)v.y, (_Float16)v.z, (_Float16)v.w };
        *(v4h*)(xh + (size_t)i * D_DIM + n * 4) = hv;
    }
}

// ---------- kernel 2: MFMA partial min over a j-chunk (R10 structure) ----------
// part[jc*N + i] = min_{j in chunk} (t[j] - 2<x_i,y_j>) = -2 max_j(<x_i,y_j>+th[j])
// A-frags load straight from pre-converted xh (8 x 16B loads, zero cvt);
// tile-0 DMA issued BEFORE the A-loads so staging overlaps the prologue.
__global__ __launch_bounds__(BLOCK) void partial_min_kernel(
    const _Float16* __restrict__ xh, const _Float16* __restrict__ yh,
    const float* __restrict__ th4, float* __restrict__ part) {
    __shared__ __align__(16) _Float16 sY[2][TJ * D_DIM];  // 2 x 16 KB
    __shared__ __align__(16) float    sTh4[2][TJ * 4];    // 2 x 2 KB

    const int tid  = threadIdx.x;
    const int lane = tid & 63, wave = tid >> 6;
    const int q = lane >> 4, n = lane & 15;
    const int jc    = blockIdx.y;
    const int jbase = jc * CHUNK;
    const int i_wave = blockIdx.x * ROWS_PER_BLOCK + wave * (GROUPS * 16);

    // ---- async stage of tile t into buffer b (XOR-swizzled on the GLOBAL side) ----
    // LDS 16B-slot sIdx holds (row = sIdx/8, chunk = (sIdx%8) ^ (row&7)).
    auto stage = [&](int t, int b) {
#pragma unroll
        for (int k = 0; k < 4; ++k) {
            const int sIdx = (k * 4 + wave) * 64 + lane;     // [0,1024)
            const int row  = sIdx >> 3;
            const int c    = (sIdx & 7) ^ (row & 7);
            const _Float16* g = yh + (size_t)(jbase + t * TJ + row) * D_DIM + c * 8;
            __builtin_amdgcn_global_load_lds(
                (const __attribute__((address_space(1))) void*)g,
                (__attribute__((address_space(3))) void*)(&sY[b][(size_t)(k * 4 + wave) * 512]),
                16, 0, 0);
        }
        // th4 tile: TJ*16 B = 2 KB via waves 0,1 (64 lanes x 16 B each)
        if (wave < 2) {
            const float* gt_ = th4 + (size_t)(jbase + t * TJ + wave * 64) * 4 + lane * 4;
            __builtin_amdgcn_global_load_lds(
                (const __attribute__((address_space(1))) void*)gt_,
                (__attribute__((address_space(3))) void*)(&sTh4[b][(size_t)wave * 256]),
                16, 0, 0);
        }
    };

    stage(0, 0);  // start tile-0 DMA first; overlaps the A-frag loads below

    // A-frags: 4 row-groups x 2 k-chunks, direct 16B f16 loads (no cvt)
    v8h a[GROUPS][2];
#pragma unroll
    for (int g = 0; g < GROUPS; ++g) {
        const _Float16* px = xh + (size_t)(i_wave + g * 16 + n) * D_DIM + q * 8;
        a[g][0] = *(const v8h*)(px);
        a[g][1] = *(const v8h*)(px + 32);
    }

    float maxs[GROUPS][4];
#pragma unroll
    for (int g = 0; g < GROUPS; ++g)
#pragma unroll
        for (int r = 0; r < 4; ++r) maxs[g][r] = -INFINITY;

    __syncthreads();  // drains vmcnt(0): tile 0 + A-frags resident

    const int sl0 = q ^ (n & 7);  // swizzled slot for chunk q of row (..8k+n)

    for (int t = 0; t < NTILE; ++t) {
        const int cur = t & 1;
        if (t + 1 < NTILE) stage(t + 1, cur ^ 1);  // prefetch under compute

        const _Float16* buf = &sY[cur][0];
        const float* tbuf = &sTh4[cur][0];
#pragma unroll 4
        for (int ss = 0; ss < TJ / 16; ++ss) {
            // row in tile = ss*16+n (row&7 == n&7); chunk q at slot sl0, q+4 at sl0^4
            const v8h b0 = *(const v8h*)(buf + (ss * 16 + n) * 64 + sl0 * 8);
            const v8h b1 = *(const v8h*)(buf + (ss * 16 + n) * 64 + (sl0 ^ 4) * 8);
            // C-quad (th splat) straight from LDS: 1 ds_read_b128, zero movs
            const v4f tv4 = *(const v4f*)(tbuf + (ss * 16 + n) * 4);
#pragma unroll
            for (int g = 0; g < GROUPS; ++g) {
                v4f acc = __builtin_amdgcn_mfma_f32_16x16x32_f16(a[g][0], b0, tv4, 0, 0, 0);
                acc     = __builtin_amdgcn_mfma_f32_16x16x32_f16(a[g][1], b1, acc, 0, 0, 0);
#pragma unroll
                for (int r = 0; r < 4; ++r)
                    maxs[g][r] = fmaxf(maxs[g][r], acc[r]);
            }
        }
        __syncthreads();  // all waves done reading buf `cur`; prefetch drained
    }

    // reduce max across the 16 j-phase lanes (lane bits 0..3), store -2*max
#pragma unroll
    for (int g = 0; g < GROUPS; ++g) {
#pragma unroll
        for (int r = 0; r < 4; ++r) {
            float v = maxs[g][r];
#pragma unroll
            for (int m = 1; m < 16; m <<= 1)
                v = fmaxf(v, __shfl_xor(v, m, 64));
            if (n == 0)
                part[(size_t)jc * N_ROWS + i_wave + g * 16 + q * 4 + r] = -2.f * v;
        }
    }
}

// ---------- kernel 3: fused reduce ----------
// out += [ sum_i min_c part[c][i] + sum(x^2) ] / N + sum(psi) / M
// x^2 read from fp32 x (exact, unchanged math).
__global__ __launch_bounds__(PBLOCK) void reduce_kernel(
    const float* __restrict__ part, const float* __restrict__ x,
    const float* __restrict__ psi, float* __restrict__ out) {
    const int tid = threadIdx.x;
    const int gt  = blockIdx.x * PBLOCK + tid;    // [0, 32768)
    float m = part[gt];
#pragma unroll
    for (int c = 1; c < JC; ++c)
        m = fminf(m, part[(size_t)c * N_ROWS + gt]);
    float s = m;
    const float4* xv = (const float4*)x;          // N*D/4 = 524288 float4
    float x2 = 0.f;
#pragma unroll
    for (int k = 0; k < 16; ++k) {
        float4 v = xv[gt + k * 32768];
        x2 += v.x * v.x + v.y * v.y + v.z * v.z + v.w * v.w;
    }
    s = (s + x2) * (1.f / (float)N_ROWS);
    if (gt < M_COLS) s += psi[gt] * (1.f / (float)M_COLS);
    for (int off = 32; off > 0; off >>= 1) s += __shfl_down(s, off, 64);
    __shared__ float tmp[4];
    if ((tid & 63) == 0) tmp[tid >> 6] = s;
    __syncthreads();
    if (tid == 0) atomicAdd(out, tmp[0] + tmp[1] + tmp[2] + tmp[3]);
}

extern "C" void kernel_launch(void* const* d_in, const int* in_sizes, int n_in,
                              void* d_out, int out_size, void* d_ws, size_t ws_size,
                              hipStream_t stream) {
    const float* x   = (const float*)d_in[0];   // [N,D]
    const float* y   = (const float*)d_in[1];   // [M,D]
    const float* psi = (const float*)d_in[2];   // [M]
    float* out = (float*)d_out;

    // workspace layout
    float* part = (float*)d_ws;                            // JC*N floats = 1 MB
    float* th4  = part + (size_t)JC * N_ROWS;              // M*4 floats = 128 KB
    _Float16* yh = (_Float16*)(th4 + (size_t)M_COLS * 4);  // M*D halves = 1 MB
    _Float16* xh = yh + (size_t)M_COLS * D_DIM;            // N*D halves = 4 MB

    prep_kernel<<<(M_COLS + N_ROWS) / 16, PBLOCK, 0, stream>>>(y, psi, x, yh, th4, xh, out);
    partial_min_kernel<<<dim3(N_ROWS / ROWS_PER_BLOCK, JC), BLOCK, 0, stream>>>(xh, yh, th4, part);
    reduce_kernel<<<N_ROWS / PBLOCK, PBLOCK, 0, stream>>>(part, x, psi, out);
}